// Round 14
// baseline (648.061 us; speedup 1.0000x reference)
//
#include <hip/hip_runtime.h>
#include <hip/hip_bf16.h>

#define CB 32
#define CN 1024
#define CE 512
#define CD 300
#define EP 512    // padded edge-row stride (floats); pow2 -> single-shift addressing.
                  // pad cols [300,320) written 0; cols [320,512) never read.
#define UCAP 320  // union-list capacity per 4-node group (mean 176, sd ~11)
#define MCAP 192  // member-list capacity per edge (deg ~ B(1024,.1): mean 102, sd 9.6)

// ---------- embedding gather: X[r,:] = emb[idx[r],:] ----------
__global__ void k_embed(const int* __restrict__ idx, const float* __restrict__ emb,
                        float* __restrict__ X) {
    int gid = blockIdx.x * blockDim.x + threadIdx.x;
    const int total = CB * CN * 75;
    if (gid >= total) return;
    int r = gid / 75, c = gid % 75;
    int e = idx[r];
    reinterpret_cast<float4*>(X)[(size_t)r * 75 + c] =
        reinterpret_cast<const float4*>(emb)[(size_t)e * 75 + c];
}

// ---------- fused: ebits words + CSR member list per edge (one wave per edge) ----------
__global__ void k_ebits_mem(const int* __restrict__ HT, unsigned long long* __restrict__ ebits,
                            unsigned short* __restrict__ mem, int* __restrict__ degs) {
    int gw = (blockIdx.x * blockDim.x + threadIdx.x) >> 6;   // b*CE+e
    int lane = threadIdx.x & 63;
    const int* hrow = HT + (size_t)gw * CN;
    unsigned short* lst = mem + (size_t)gw * MCAP;
    int base = 0;
    unsigned long long lmask = (1ull << lane) - 1ull;
#pragma unroll
    for (int c = 0; c < 16; ++c) {
        unsigned long long bal = __ballot(hrow[(c << 6) + lane] != 0);
        if (lane == 0) ebits[(size_t)gw * 16 + c] = bal;
        if ((bal >> lane) & 1ull) {
            int off = base + (int)__popcll(bal & lmask);
            if (off < MCAP) lst[off] = (unsigned short)((c << 6) + lane);
        }
        base += (int)__popcll(bal);
    }
    if (lane == 0) degs[gw] = base;   // may exceed MCAP -> fallback path
}

// ---------- nbits = bit-transpose of ebits ----------
__global__ __launch_bounds__(512) void k_bitT(const unsigned long long* __restrict__ ebits,
        unsigned long long* __restrict__ nbits) {
    __shared__ unsigned long long w[8][64];
    int b = blockIdx.x >> 4, nc = blockIdx.x & 15;
    int tid = threadIdx.x, ec = tid >> 6, lane = tid & 63;
    w[ec][lane] = ebits[((size_t)b * CE + (ec << 6) + lane) * 16 + nc];
    __syncthreads();
    unsigned long long out = 0;
#pragma unroll
    for (int j = 0; j < 64; ++j)
        out |= ((w[ec][j] >> lane) & 1ull) << j;
    nbits[((size_t)b * CN + (nc << 6) + lane) * 8 + ec] = out;
}

// ---------- k_prep: vecs = 6 folded attention vectors ----------
__global__ void k_prep(const float* __restrict__ w2_1, const float* __restrict__ w3_1,
                       const float* __restrict__ a_1, const float* __restrict__ a2_1,
                       const float* __restrict__ w2_2, const float* __restrict__ w3_2,
                       const float* __restrict__ a_2, const float* __restrict__ a2_2,
                       float* __restrict__ vecs) {
    int which = blockIdx.x;
    int t = threadIdx.x;
    if (t >= CD) return;
    const float* W; const float* v;
    switch (which) {
        case 0:  W = w2_1; v = a_1 + CD;  break;
        case 1:  W = w2_1; v = a2_1;      break;
        case 2:  W = w3_1; v = a2_1 + CD; break;
        case 3:  W = w2_2; v = a_2 + CD;  break;
        case 4:  W = w2_2; v = a2_2;      break;
        default: W = w3_2; v = a2_2 + CD; break;
    }
    float s = 0.f;
    for (int j = 0; j < CD; ++j) s += W[(size_t)t * CD + j] * v[j];
    vecs[which * CD + t] = s;
}

// ---------- C[M,300] = A[M,300(lda)] @ W[300,300] ----------
__global__ __launch_bounds__(256) void k_gemm300(const float* __restrict__ A,
                                                 const float* __restrict__ W,
                                                 float* __restrict__ C, int M,
                                                 int lda, int ldc) {
    __shared__ float As[64][20];
    __shared__ float Ws[16][68];
    int tid = threadIdx.x;
    int n0 = blockIdx.x * 64, m0 = blockIdx.y * 64;
    int tx = tid & 15, ty = tid >> 4;
    int la_r = tid >> 2, la_c = (tid & 3) << 2;
    int lw_r = tid >> 4, lw_c = (tid & 15) << 2;
    float acc[4][4] = {};
    for (int k0 = 0; k0 < CD; k0 += 16) {
        {
            int kc = k0 + la_c;
            const float* Ap = A + (size_t)(m0 + la_r) * lda + kc;
            float4 av;
            if (kc + 3 < CD) av = *reinterpret_cast<const float4*>(Ap);
            else {
                av.x = kc     < CD ? Ap[0] : 0.f;
                av.y = kc + 1 < CD ? Ap[1] : 0.f;
                av.z = kc + 2 < CD ? Ap[2] : 0.f;
                av.w = 0.f;
            }
            *reinterpret_cast<float4*>(&As[la_r][la_c]) = av;
        }
        {
            int kr = k0 + lw_r;
            float4 wv = {0.f, 0.f, 0.f, 0.f};
            if (kr < CD) {
                const float* Wp = W + (size_t)kr * CD + n0 + lw_c;
                if (n0 + lw_c + 3 < CD) wv = *reinterpret_cast<const float4*>(Wp);
                else {
                    if (n0 + lw_c     < CD) wv.x = Wp[0];
                    if (n0 + lw_c + 1 < CD) wv.y = Wp[1];
                    if (n0 + lw_c + 2 < CD) wv.z = Wp[2];
                }
            }
            *reinterpret_cast<float4*>(&Ws[lw_r][lw_c]) = wv;
        }
        __syncthreads();
#pragma unroll
        for (int k = 0; k < 16; ++k) {
            float av[4];
#pragma unroll
            for (int i = 0; i < 4; ++i) av[i] = As[ty * 4 + i][k];
            float4 bv = *reinterpret_cast<const float4*>(&Ws[k][tx * 4]);
            float bb[4] = {bv.x, bv.y, bv.z, bv.w};
#pragma unroll
            for (int i = 0; i < 4; ++i)
#pragma unroll
                for (int j = 0; j < 4; ++j) acc[i][j] += av[i] * bb[j];
        }
        __syncthreads();
    }
    for (int i = 0; i < 4; ++i) {
        int m = m0 + ty * 4 + i;
        int n = n0 + tx * 4;
        float* Cp = C + (size_t)m * ldc + n;
        if (n + 3 < CD) {
            float4 v = {acc[i][0], acc[i][1], acc[i][2], acc[i][3]};
            *reinterpret_cast<float4*>(Cp) = v;
        } else {
            for (int j = 0; j < 4; ++j) if (n + j < CD) Cp[j] = acc[i][j];
        }
    }
}

// ---------- s1[r] = leaky(wc·a_top + X[r,:]·av), p[r] = X[r,:]·pv ----------
__global__ void k_score(const float* __restrict__ X, const float* __restrict__ av,
                        const float* __restrict__ pv, const float* __restrict__ wc,
                        const float* __restrict__ a_orig,
                        float alpha, float* __restrict__ s1, float* __restrict__ p, int M) {
    int gw = (blockIdx.x * blockDim.x + threadIdx.x) >> 6;
    int lane = threadIdx.x & 63;
    if (gw >= M) return;
    const float* row = X + (size_t)gw * CD;
    float d1 = 0.f, d2 = 0.f, dc = 0.f;
    for (int d = lane; d < CD; d += 64) {
        float x = row[d];
        d1 += x * av[d];
        d2 += x * pv[d];
        dc += wc[d] * a_orig[d];
    }
    for (int o = 32; o; o >>= 1) {
        d1 += __shfl_down(d1, o);
        d2 += __shfl_down(d2, o);
        dc += __shfl_down(dc, o);
    }
    if (lane == 0) {
        float v = dc + d1;
        s1[gw] = v > 0.f ? v : alpha * v;
        p[gw] = d2;
    }
}

// ---------- per-batch max over s1, e1 = exp(s1 - max) ----------
__global__ __launch_bounds__(1024) void k_bmax(const float* __restrict__ s1,
                                               float* __restrict__ e1) {
    __shared__ float red[16];
    int b = blockIdx.x, t = threadIdx.x;
    float v = s1[b * CN + t];
    float m = v;
    for (int o = 32; o; o >>= 1) m = fmaxf(m, __shfl_xor(m, o));
    if ((t & 63) == 0) red[t >> 6] = m;
    __syncthreads();
    if (t == 0) {
        float mm = red[0];
        for (int i = 1; i < 16; ++i) mm = fmaxf(mm, red[i]);
        red[0] = mm;
    }
    __syncthreads();
    e1[b * CN + t] = __expf(v - red[0]);
}

// ---------- sparse edge aggregation + fused q (CSR, unroll-8, XCD-pinned batches) ----------
// Block i -> batch b with b%8 == i%8 (bijective, 4096%8==0): each XCD's L2 keeps
// its 4 batches' X rows (~4.8 MB) resident across the ~51x per-row reuse.
__global__ __launch_bounds__(256) void k_edge_agg(const unsigned short* __restrict__ mem,
        const int* __restrict__ degs, const unsigned long long* __restrict__ ebits,
        const float* __restrict__ e1, const float* __restrict__ Xs,
        const float* __restrict__ qvec, float* __restrict__ edge, float* __restrict__ q) {
    int i0 = blockIdx.x;
    int r = i0 & 7, t = i0 >> 3;        // t in 0..511
    int b = (t >> 7) * 8 + r;           // 4 batches per XCD slot
    int j = t & 127;                    // edge-quad within batch
    int gw = b * CE + (j << 2) + (threadIdx.x >> 6);
    int lane = threadIdx.x & 63;
    const float* e1b = e1 + b * CN;
    const float* Xb = Xs + (size_t)b * CN * CD;
    int deg = degs[gw];
    float a0 = 0.f, a1 = 0.f, a2 = 0.f, a3 = 0.f, a4 = 0.f;
    float den = 0.f;
    bool tail = lane < (CD - 256);
    if (deg <= MCAP) {
        const unsigned short* lst = mem + (size_t)gw * MCAP;
        int i = 0;
        for (; i + 8 <= deg; i += 8) {
            ushort4 na = *reinterpret_cast<const ushort4*>(lst + i);
            ushort4 nb = *reinterpret_cast<const ushort4*>(lst + i + 4);
            float w0 = e1b[na.x], w1 = e1b[na.y], w2 = e1b[na.z], w3 = e1b[na.w];
            float w4 = e1b[nb.x], w5 = e1b[nb.y], w6 = e1b[nb.z], w7 = e1b[nb.w];
            const float* r0 = Xb + (size_t)na.x * CD;
            const float* r1 = Xb + (size_t)na.y * CD;
            const float* r2 = Xb + (size_t)na.z * CD;
            const float* r3 = Xb + (size_t)na.w * CD;
            const float* r4 = Xb + (size_t)nb.x * CD;
            const float* r5 = Xb + (size_t)nb.y * CD;
            const float* r6 = Xb + (size_t)nb.z * CD;
            const float* r7 = Xb + (size_t)nb.w * CD;
            float v00 = r0[lane], v01 = r0[lane + 64], v02 = r0[lane + 128], v03 = r0[lane + 192];
            float v10 = r1[lane], v11 = r1[lane + 64], v12 = r1[lane + 128], v13 = r1[lane + 192];
            float v20 = r2[lane], v21 = r2[lane + 64], v22 = r2[lane + 128], v23 = r2[lane + 192];
            float v30 = r3[lane], v31 = r3[lane + 64], v32 = r3[lane + 128], v33 = r3[lane + 192];
            float v40 = r4[lane], v41 = r4[lane + 64], v42 = r4[lane + 128], v43 = r4[lane + 192];
            float v50 = r5[lane], v51 = r5[lane + 64], v52 = r5[lane + 128], v53 = r5[lane + 192];
            float v60 = r6[lane], v61 = r6[lane + 64], v62 = r6[lane + 128], v63 = r6[lane + 192];
            float v70 = r7[lane], v71 = r7[lane + 64], v72 = r7[lane + 128], v73 = r7[lane + 192];
            float v04 = 0.f, v14 = 0.f, v24 = 0.f, v34 = 0.f;
            float v44 = 0.f, v54 = 0.f, v64 = 0.f, v74 = 0.f;
            if (tail) {
                v04 = r0[lane + 256]; v14 = r1[lane + 256]; v24 = r2[lane + 256]; v34 = r3[lane + 256];
                v44 = r4[lane + 256]; v54 = r5[lane + 256]; v64 = r6[lane + 256]; v74 = r7[lane + 256];
            }
            den += w0; den += w1; den += w2; den += w3;
            den += w4; den += w5; den += w6; den += w7;
            a0 += w0 * v00; a0 += w1 * v10; a0 += w2 * v20; a0 += w3 * v30;
            a0 += w4 * v40; a0 += w5 * v50; a0 += w6 * v60; a0 += w7 * v70;
            a1 += w0 * v01; a1 += w1 * v11; a1 += w2 * v21; a1 += w3 * v31;
            a1 += w4 * v41; a1 += w5 * v51; a1 += w6 * v61; a1 += w7 * v71;
            a2 += w0 * v02; a2 += w1 * v12; a2 += w2 * v22; a2 += w3 * v32;
            a2 += w4 * v42; a2 += w5 * v52; a2 += w6 * v62; a2 += w7 * v72;
            a3 += w0 * v03; a3 += w1 * v13; a3 += w2 * v23; a3 += w3 * v33;
            a3 += w4 * v43; a3 += w5 * v53; a3 += w6 * v63; a3 += w7 * v73;
            a4 += w0 * v04; a4 += w1 * v14; a4 += w2 * v24; a4 += w3 * v34;
            a4 += w4 * v44; a4 += w5 * v54; a4 += w6 * v64; a4 += w7 * v74;
        }
        for (; i + 4 <= deg; i += 4) {
            ushort4 nn = *reinterpret_cast<const ushort4*>(lst + i);
            float w0 = e1b[nn.x], w1 = e1b[nn.y], w2 = e1b[nn.z], w3 = e1b[nn.w];
            const float* r0 = Xb + (size_t)nn.x * CD;
            const float* r1 = Xb + (size_t)nn.y * CD;
            const float* r2 = Xb + (size_t)nn.z * CD;
            const float* r3 = Xb + (size_t)nn.w * CD;
            float v00 = r0[lane], v01 = r0[lane + 64], v02 = r0[lane + 128], v03 = r0[lane + 192];
            float v10 = r1[lane], v11 = r1[lane + 64], v12 = r1[lane + 128], v13 = r1[lane + 192];
            float v20 = r2[lane], v21 = r2[lane + 64], v22 = r2[lane + 128], v23 = r2[lane + 192];
            float v30 = r3[lane], v31 = r3[lane + 64], v32 = r3[lane + 128], v33 = r3[lane + 192];
            float v04 = 0.f, v14 = 0.f, v24 = 0.f, v34 = 0.f;
            if (tail) { v04 = r0[lane + 256]; v14 = r1[lane + 256]; v24 = r2[lane + 256]; v34 = r3[lane + 256]; }
            den += w0; den += w1; den += w2; den += w3;
            a0 += w0 * v00; a0 += w1 * v10; a0 += w2 * v20; a0 += w3 * v30;
            a1 += w0 * v01; a1 += w1 * v11; a1 += w2 * v21; a1 += w3 * v31;
            a2 += w0 * v02; a2 += w1 * v12; a2 += w2 * v22; a2 += w3 * v32;
            a3 += w0 * v03; a3 += w1 * v13; a3 += w2 * v23; a3 += w3 * v33;
            a4 += w0 * v04; a4 += w1 * v14; a4 += w2 * v24; a4 += w3 * v34;
        }
        for (; i < deg; ++i) {
            int n = lst[i];
            float w = e1b[n];
            const float* r = Xb + (size_t)n * CD;
            den += w;
            a0 += w * r[lane];
            a1 += w * r[lane + 64];
            a2 += w * r[lane + 128];
            a3 += w * r[lane + 192];
            if (tail) a4 += w * r[lane + 256];
        }
    } else {   // overflow fallback (P~1e-20): ebits/ballot path
        const unsigned long long* eb = ebits + (size_t)gw * 16;
#pragma unroll
        for (int c = 0; c < 16; ++c) {
            int n0 = c << 6;
            float wv = e1b[n0 + lane];
            unsigned long long bal = eb[c];
            while (bal) {
                int jj = (int)__ffsll(bal) - 1;
                bal &= bal - 1ull;
                float w = __shfl(wv, jj);
                const float* row = Xb + (size_t)(n0 + jj) * CD;
                den += w;
                a0 += w * row[lane];
                a1 += w * row[lane + 64];
                a2 += w * row[lane + 128];
                a3 += w * row[lane + 192];
                if (tail) a4 += w * row[lane + 256];
            }
        }
    }
    float inv = deg > 0 ? 1.f / den : 0.f;
    float o0 = a0 * inv, o1 = a1 * inv, o2 = a2 * inv, o3 = a3 * inv;
    float o4 = tail ? a4 * inv : 0.f;
    float* erow = edge + (size_t)gw * EP;
    erow[lane]       = o0;
    erow[lane + 64]  = o1;
    erow[lane + 128] = o2;
    erow[lane + 192] = o3;
    erow[lane + 256] = o4;   // lanes 44..63 zero floats 300..319 (f4 slots 75..79)
    float d2 = o0 * qvec[lane];
    d2 += o1 * qvec[lane + 64];
    d2 += o2 * qvec[lane + 128];
    d2 += o3 * qvec[lane + 192];
    if (tail) d2 += o4 * qvec[lane + 256];
    for (int o = 32; o; o >>= 1) d2 += __shfl_down(d2, o);
    if (lane == 0) q[gw] = d2;
}

// ---------- fused node attention (R8-proven): nbits masks + compacted weights ----------
// EP=512 -> edge-row addressing is e<<7 float4s (single shift); phase-2 main loop
// unrolled 16-deep for 16 outstanding dwordx4 loads per wave.
#define ACC16(vv, ww) do { \
    acc[0][0] += (ww).x * (vv).x; acc[0][1] += (ww).x * (vv).y; \
    acc[0][2] += (ww).x * (vv).z; acc[0][3] += (ww).x * (vv).w; \
    acc[1][0] += (ww).y * (vv).x; acc[1][1] += (ww).y * (vv).y; \
    acc[1][2] += (ww).y * (vv).z; acc[1][3] += (ww).y * (vv).w; \
    acc[2][0] += (ww).z * (vv).x; acc[2][1] += (ww).z * (vv).y; \
    acc[2][2] += (ww).z * (vv).z; acc[2][3] += (ww).z * (vv).w; \
    acc[3][0] += (ww).w * (vv).x; acc[3][1] += (ww).w * (vv).y; \
    acc[3][2] += (ww).w * (vv).z; acc[3][3] += (ww).w * (vv).w; \
} while (0)

__global__ __launch_bounds__(320) void k_node_attn(const unsigned long long* __restrict__ nbits,
        const float* __restrict__ p, const float* __restrict__ q,
        const float* __restrict__ edge, float alpha, int do_elu, float* __restrict__ out) {
    __shared__ float4 wsc[4][UCAP];
    __shared__ __align__(8) unsigned short ul[4][UCAP];
    __shared__ int ucnt_s[4], flag_s[4];
    __shared__ float gpn[16], gmx[16], gsc[16];
    __shared__ int gct[16];
    int blk = blockIdx.x;
    int b = blk >> 6, n0 = (blk & 63) << 4;
    int tid = threadIdx.x, wv = tid >> 6, lane = tid & 63;
    const float* qb = q + b * CE;

    if (wv < 4) {
        float pn[4]; const unsigned long long* nb[4];
#pragma unroll
        for (int k = 0; k < 4; ++k) {
            int n = n0 + 4 * wv + k;
            pn[k] = p[b * CN + n];
            nb[k] = nbits + ((size_t)b * CN + n) * 8;
        }
        float sc[4][8];
        int cnt[4] = {0, 0, 0, 0};
        float mx[4] = {-3.4e38f, -3.4e38f, -3.4e38f, -3.4e38f};
        int ubits = 0;
#pragma unroll
        for (int j = 0; j < 8; ++j) {
            int e = lane + (j << 6);
            float qe = qb[e];
            int many = 0;
#pragma unroll
            for (int k = 0; k < 4; ++k) {
                int m = (int)((nb[k][j] >> lane) & 1ull);
                float v = pn[k] + qe;
                v = v > 0.f ? v : alpha * v;
                v = m ? v : -3.0e38f;
                cnt[k] += m; many |= m;
                mx[k] = fmaxf(mx[k], v);
                sc[k][j] = v;
            }
            ubits |= (many ? 1 : 0) << j;
        }
#pragma unroll
        for (int k = 0; k < 4; ++k) {
            for (int o = 32; o; o >>= 1) {
                mx[k] = fmaxf(mx[k], __shfl_xor(mx[k], o));
                cnt[k] += __shfl_xor(cnt[k], o);
            }
        }
        float scale[4];
#pragma unroll
        for (int k = 0; k < 4; ++k) {
            float s = 0.f;
#pragma unroll
            for (int j = 0; j < 8; ++j) { float w8 = __expf(sc[k][j] - mx[k]); sc[k][j] = w8; s += w8; }
            for (int o = 32; o; o >>= 1) s += __shfl_xor(s, o);
            scale[k] = cnt[k] > 0 ? 1.f / s : 1.f;
        }
        int base = 0;
        unsigned long long lmask = (1ull << lane) - 1ull;
#pragma unroll
        for (int j = 0; j < 8; ++j) {
            unsigned long long bal = __ballot((ubits >> j) & 1);
            if ((ubits >> j) & 1) {
                int off = base + (int)__popcll(bal & lmask);
                if (off < UCAP) {
                    ul[wv][off] = (unsigned short)(lane + (j << 6));
                    wsc[wv][off] = make_float4(sc[0][j] * scale[0], sc[1][j] * scale[1],
                                               sc[2][j] * scale[2], sc[3][j] * scale[3]);
                }
            }
            base += (int)__popcll(bal);
        }
        if (lane == 0) {
            ucnt_s[wv] = base < UCAP ? base : UCAP;
            flag_s[wv] = (cnt[0] == 0) | (cnt[1] == 0) | (cnt[2] == 0) | (cnt[3] == 0) |
                         (base > UCAP);
            gpn[wv*4+0]=pn[0]; gmx[wv*4+0]=mx[0]; gsc[wv*4+0]=scale[0]; gct[wv*4+0]=cnt[0];
            gpn[wv*4+1]=pn[1]; gmx[wv*4+1]=mx[1]; gsc[wv*4+1]=scale[1]; gct[wv*4+1]=cnt[1];
            gpn[wv*4+2]=pn[2]; gmx[wv*4+2]=mx[2]; gsc[wv*4+2]=scale[2]; gct[wv*4+2]=cnt[2];
            gpn[wv*4+3]=pn[3]; gmx[wv*4+3]=mx[3]; gsc[wv*4+3]=scale[3]; gct[wv*4+3]=cnt[3];
        }
    }
    __syncthreads();

    int grp = tid / 80;
    int j4 = tid - grp * 80;
    const float4* eb4 = reinterpret_cast<const float4*>(edge + (size_t)b * CE * EP) + j4;
    int cnt = ucnt_s[grp], bad = flag_s[grp];
    float acc[4][4] = {};
    if (!bad) {
        int i = 0;
        for (; i + 16 <= cnt; i += 16) {
            ushort4 ua = *reinterpret_cast<const ushort4*>(&ul[grp][i]);
            ushort4 ub = *reinterpret_cast<const ushort4*>(&ul[grp][i + 4]);
            ushort4 uc = *reinterpret_cast<const ushort4*>(&ul[grp][i + 8]);
            ushort4 ud = *reinterpret_cast<const ushort4*>(&ul[grp][i + 12]);
            float4 v0 = eb4[(size_t)ua.x << 7], v1 = eb4[(size_t)ua.y << 7];
            float4 v2 = eb4[(size_t)ua.z << 7], v3 = eb4[(size_t)ua.w << 7];
            float4 v4 = eb4[(size_t)ub.x << 7], v5 = eb4[(size_t)ub.y << 7];
            float4 v6 = eb4[(size_t)ub.z << 7], v7 = eb4[(size_t)ub.w << 7];
            float4 v8 = eb4[(size_t)uc.x << 7], v9 = eb4[(size_t)uc.y << 7];
            float4 va = eb4[(size_t)uc.z << 7], vb = eb4[(size_t)uc.w << 7];
            float4 vc = eb4[(size_t)ud.x << 7], vd = eb4[(size_t)ud.y << 7];
            float4 ve = eb4[(size_t)ud.z << 7], vf = eb4[(size_t)ud.w << 7];
            { float4 w = wsc[grp][i];      ACC16(v0, w); }
            { float4 w = wsc[grp][i + 1];  ACC16(v1, w); }
            { float4 w = wsc[grp][i + 2];  ACC16(v2, w); }
            { float4 w = wsc[grp][i + 3];  ACC16(v3, w); }
            { float4 w = wsc[grp][i + 4];  ACC16(v4, w); }
            { float4 w = wsc[grp][i + 5];  ACC16(v5, w); }
            { float4 w = wsc[grp][i + 6];  ACC16(v6, w); }
            { float4 w = wsc[grp][i + 7];  ACC16(v7, w); }
            { float4 w = wsc[grp][i + 8];  ACC16(v8, w); }
            { float4 w = wsc[grp][i + 9];  ACC16(v9, w); }
            { float4 w = wsc[grp][i + 10]; ACC16(va, w); }
            { float4 w = wsc[grp][i + 11]; ACC16(vb, w); }
            { float4 w = wsc[grp][i + 12]; ACC16(vc, w); }
            { float4 w = wsc[grp][i + 13]; ACC16(vd, w); }
            { float4 w = wsc[grp][i + 14]; ACC16(ve, w); }
            { float4 w = wsc[grp][i + 15]; ACC16(vf, w); }
        }
        for (; i + 8 <= cnt; i += 8) {
            ushort4 ua = *reinterpret_cast<const ushort4*>(&ul[grp][i]);
            ushort4 ub = *reinterpret_cast<const ushort4*>(&ul[grp][i + 4]);
            float4 v0 = eb4[(size_t)ua.x << 7], v1 = eb4[(size_t)ua.y << 7];
            float4 v2 = eb4[(size_t)ua.z << 7], v3 = eb4[(size_t)ua.w << 7];
            float4 v4 = eb4[(size_t)ub.x << 7], v5 = eb4[(size_t)ub.y << 7];
            float4 v6 = eb4[(size_t)ub.z << 7], v7 = eb4[(size_t)ub.w << 7];
            { float4 w = wsc[grp][i];     ACC16(v0, w); }
            { float4 w = wsc[grp][i + 1]; ACC16(v1, w); }
            { float4 w = wsc[grp][i + 2]; ACC16(v2, w); }
            { float4 w = wsc[grp][i + 3]; ACC16(v3, w); }
            { float4 w = wsc[grp][i + 4]; ACC16(v4, w); }
            { float4 w = wsc[grp][i + 5]; ACC16(v5, w); }
            { float4 w = wsc[grp][i + 6]; ACC16(v6, w); }
            { float4 w = wsc[grp][i + 7]; ACC16(v7, w); }
        }
        for (; i < cnt; ++i) {
            int e = ul[grp][i];
            float4 v = eb4[(size_t)e << 7];
            float4 w = wsc[grp][i];
            ACC16(v, w);
        }
    } else {
        float pnk[4], mxk[4], sck[4]; int ctk[4];
        const unsigned long long* nbr[4];
#pragma unroll
        for (int k = 0; k < 4; ++k) {
            pnk[k] = gpn[grp*4+k]; mxk[k] = gmx[grp*4+k]; sck[k] = gsc[grp*4+k]; ctk[k] = gct[grp*4+k];
            nbr[k] = nbits + ((size_t)b * CN + n0 + grp * 4 + k) * 8;
        }
        for (int e = 0; e < CE; ++e) {
            float4 v = eb4[(size_t)e << 7];
            float qe = qb[e];
#pragma unroll
            for (int k = 0; k < 4; ++k) {
                int m = (int)((nbr[k][e >> 6] >> (e & 63)) & 1ull);
                float vv = pnk[k] + qe; vv = vv > 0.f ? vv : alpha * vv;
                float w = ctk[k] == 0 ? (1.f / CE) : (m ? __expf(vv - mxk[k]) * sck[k] : 0.f);
                acc[k][0] += w * v.x; acc[k][1] += w * v.y; acc[k][2] += w * v.z; acc[k][3] += w * v.w;
            }
        }
    }
    if (j4 < 75) {
#pragma unroll
        for (int ni = 0; ni < 4; ++ni) {
            float4 o = {acc[ni][0], acc[ni][1], acc[ni][2], acc[ni][3]};
            if (do_elu) {
                o.x = o.x > 0.f ? o.x : expm1f(o.x);
                o.y = o.y > 0.f ? o.y : expm1f(o.y);
                o.z = o.z > 0.f ? o.z : expm1f(o.z);
                o.w = o.w > 0.f ? o.w : expm1f(o.w);
            }
            *reinterpret_cast<float4*>(out + ((size_t)b * CN + n0 + grp * 4 + ni) * CD + j4 * 4) = o;
        }
    }
}

extern "C" void kernel_launch(void* const* d_in, const int* in_sizes, int n_in,
                              void* d_out, int out_size, void* d_ws, size_t ws_size,
                              hipStream_t stream) {
    const int*   inputs = (const int*)d_in[0];
    const int*   HT     = (const int*)d_in[1];
    const float* emb    = (const float*)d_in[2];
    const float* w2_1   = (const float*)d_in[3];
    const float* w3_1   = (const float*)d_in[4];
    const float* a_1    = (const float*)d_in[5];
    const float* a2_1   = (const float*)d_in[6];
    const float* wc_1   = (const float*)d_in[7];
    const float* w_2    = (const float*)d_in[8];
    const float* w2_2   = (const float*)d_in[9];
    const float* w3_2   = (const float*)d_in[10];
    const float* a_2    = (const float*)d_in[11];
    const float* a2_2   = (const float*)d_in[12];
    const float* wc_2   = (const float*)d_in[13];

    char* ws = (char*)d_ws;
    float* big0               = (float*)(ws);                          // 39,321,600 B: X0 -> X1
    float* big1               = (float*)(ws + 39321600);               // 39,321,600 B: XW
    float* edge               = (float*)(ws + 78643200);               // 33,554,432 B (EP=512)
    unsigned long long* ebits = (unsigned long long*)(ws + 112197632); //  2,097,152 B
    unsigned long long* nbits = (unsigned long long*)(ws + 114294784); //  2,097,152 B
    unsigned short* mem       = (unsigned short*)(ws + 116391936);     //  6,291,456 B
    int* degs                 = (int*)(ws + 122683392);                //     65,536 B
    float* s1                 = (float*)(ws + 122748928);              //    131,072 B
    float* p                  = (float*)(ws + 122880000);              //    131,072 B
    float* e1                 = (float*)(ws + 123011072);              //    131,072 B
    float* qv                 = (float*)(ws + 123142144);              //     65,536 B
    float* vecs               = (float*)(ws + 123207680);              //      7,200 B
    // total: 123,214,880 B

    k_embed<<<9600, 256, 0, stream>>>(inputs, emb, big0);
    k_ebits_mem<<<4096, 256, 0, stream>>>(HT, ebits, mem, degs);
    k_bitT<<<512, 512, 0, stream>>>(ebits, nbits);
    k_prep<<<6, 320, 0, stream>>>(w2_1, w3_1, a_1, a2_1, w2_2, w3_2, a_2, a2_2, vecs);

    // ---- layer 1: transfer=False, concat=True (ELU), alpha=0.1 ----
    k_score<<<CB * CN / 4, 256, 0, stream>>>(big0, vecs, vecs + CD, wc_1, a_1, 0.1f, s1, p, CB * CN);
    k_bmax<<<CB, 1024, 0, stream>>>(s1, e1);
    k_edge_agg<<<4096, 256, 0, stream>>>(mem, degs, ebits, e1, big0, vecs + 2 * CD, edge, qv);
    k_node_attn<<<2048, 320, 0, stream>>>(nbits, p, qv, edge, 0.1f, 1, big0);   // X1 -> big0

    // ---- layer 2: transfer=True, concat=False, alpha=0.2 ----
    k_score<<<CB * CN / 4, 256, 0, stream>>>(big0, vecs + 3 * CD, vecs + 4 * CD, wc_2, a_2, 0.2f, s1, p, CB * CN);
    k_gemm300<<<dim3(5, 512), 256, 0, stream>>>(big0, w_2, big1, CB * CN, CD, CD);   // XW = X1 @ w_2
    k_bmax<<<CB, 1024, 0, stream>>>(s1, e1);
    k_edge_agg<<<4096, 256, 0, stream>>>(mem, degs, ebits, e1, big1, vecs + 5 * CD, edge, qv);
    k_node_attn<<<2048, 320, 0, stream>>>(nbits, p, qv, edge, 0.2f, 0, (float*)d_out);
}

// Round 15
// 600.696 us; speedup vs baseline: 1.0788x; 1.0788x over previous
//
#include <hip/hip_runtime.h>
#include <hip/hip_bf16.h>

#define CB 32
#define CN 1024
#define CE 512
#define CD 300
#define EP 320    // padded edge-row stride (floats); pad cols [300,320) are written 0.
                  // NOT a power of two: pow2 stride (R14, EP=512) caused L2 set-aliasing, -15%.
#define UCAP 320  // union-list capacity per 4-node group (mean 176, sd ~11)
#define MCAP 192  // member-list capacity per edge (deg ~ B(1024,.1): mean 102, sd 9.6)

// ---------- embedding gather: X[r,:] = emb[idx[r],:] ----------
__global__ void k_embed(const int* __restrict__ idx, const float* __restrict__ emb,
                        float* __restrict__ X) {
    int gid = blockIdx.x * blockDim.x + threadIdx.x;
    const int total = CB * CN * 75;
    if (gid >= total) return;
    int r = gid / 75, c = gid % 75;
    int e = idx[r];
    reinterpret_cast<float4*>(X)[(size_t)r * 75 + c] =
        reinterpret_cast<const float4*>(emb)[(size_t)e * 75 + c];
}

// ---------- fused: ebits words + CSR member list per edge (one wave per edge) ----------
__global__ void k_ebits_mem(const int* __restrict__ HT, unsigned long long* __restrict__ ebits,
                            unsigned short* __restrict__ mem, int* __restrict__ degs) {
    int gw = (blockIdx.x * blockDim.x + threadIdx.x) >> 6;   // b*CE+e
    int lane = threadIdx.x & 63;
    const int* hrow = HT + (size_t)gw * CN;
    unsigned short* lst = mem + (size_t)gw * MCAP;
    int base = 0;
    unsigned long long lmask = (1ull << lane) - 1ull;
#pragma unroll
    for (int c = 0; c < 16; ++c) {
        unsigned long long bal = __ballot(hrow[(c << 6) + lane] != 0);
        if (lane == 0) ebits[(size_t)gw * 16 + c] = bal;
        if ((bal >> lane) & 1ull) {
            int off = base + (int)__popcll(bal & lmask);
            if (off < MCAP) lst[off] = (unsigned short)((c << 6) + lane);
        }
        base += (int)__popcll(bal);
    }
    if (lane == 0) degs[gw] = base;   // may exceed MCAP -> fallback path
}

// ---------- nbits = bit-transpose of ebits ----------
__global__ __launch_bounds__(512) void k_bitT(const unsigned long long* __restrict__ ebits,
        unsigned long long* __restrict__ nbits) {
    __shared__ unsigned long long w[8][64];
    int b = blockIdx.x >> 4, nc = blockIdx.x & 15;
    int tid = threadIdx.x, ec = tid >> 6, lane = tid & 63;
    w[ec][lane] = ebits[((size_t)b * CE + (ec << 6) + lane) * 16 + nc];
    __syncthreads();
    unsigned long long out = 0;
#pragma unroll
    for (int j = 0; j < 64; ++j)
        out |= ((w[ec][j] >> lane) & 1ull) << j;
    nbits[((size_t)b * CN + (nc << 6) + lane) * 8 + ec] = out;
}

// ---------- k_prep: vecs = 6 folded attention vectors ----------
__global__ void k_prep(const float* __restrict__ w2_1, const float* __restrict__ w3_1,
                       const float* __restrict__ a_1, const float* __restrict__ a2_1,
                       const float* __restrict__ w2_2, const float* __restrict__ w3_2,
                       const float* __restrict__ a_2, const float* __restrict__ a2_2,
                       float* __restrict__ vecs) {
    int which = blockIdx.x;
    int t = threadIdx.x;
    if (t >= CD) return;
    const float* W; const float* v;
    switch (which) {
        case 0:  W = w2_1; v = a_1 + CD;  break;
        case 1:  W = w2_1; v = a2_1;      break;
        case 2:  W = w3_1; v = a2_1 + CD; break;
        case 3:  W = w2_2; v = a_2 + CD;  break;
        case 4:  W = w2_2; v = a2_2;      break;
        default: W = w3_2; v = a2_2 + CD; break;
    }
    float s = 0.f;
    for (int j = 0; j < CD; ++j) s += W[(size_t)t * CD + j] * v[j];
    vecs[which * CD + t] = s;
}

// ---------- C[M,300] = A[M,300(lda)] @ W[300,300] ----------
__global__ __launch_bounds__(256) void k_gemm300(const float* __restrict__ A,
                                                 const float* __restrict__ W,
                                                 float* __restrict__ C, int M,
                                                 int lda, int ldc) {
    __shared__ float As[64][20];
    __shared__ float Ws[16][68];
    int tid = threadIdx.x;
    int n0 = blockIdx.x * 64, m0 = blockIdx.y * 64;
    int tx = tid & 15, ty = tid >> 4;
    int la_r = tid >> 2, la_c = (tid & 3) << 2;
    int lw_r = tid >> 4, lw_c = (tid & 15) << 2;
    float acc[4][4] = {};
    for (int k0 = 0; k0 < CD; k0 += 16) {
        {
            int kc = k0 + la_c;
            const float* Ap = A + (size_t)(m0 + la_r) * lda + kc;
            float4 av;
            if (kc + 3 < CD) av = *reinterpret_cast<const float4*>(Ap);
            else {
                av.x = kc     < CD ? Ap[0] : 0.f;
                av.y = kc + 1 < CD ? Ap[1] : 0.f;
                av.z = kc + 2 < CD ? Ap[2] : 0.f;
                av.w = 0.f;
            }
            *reinterpret_cast<float4*>(&As[la_r][la_c]) = av;
        }
        {
            int kr = k0 + lw_r;
            float4 wv = {0.f, 0.f, 0.f, 0.f};
            if (kr < CD) {
                const float* Wp = W + (size_t)kr * CD + n0 + lw_c;
                if (n0 + lw_c + 3 < CD) wv = *reinterpret_cast<const float4*>(Wp);
                else {
                    if (n0 + lw_c     < CD) wv.x = Wp[0];
                    if (n0 + lw_c + 1 < CD) wv.y = Wp[1];
                    if (n0 + lw_c + 2 < CD) wv.z = Wp[2];
                }
            }
            *reinterpret_cast<float4*>(&Ws[lw_r][lw_c]) = wv;
        }
        __syncthreads();
#pragma unroll
        for (int k = 0; k < 16; ++k) {
            float av[4];
#pragma unroll
            for (int i = 0; i < 4; ++i) av[i] = As[ty * 4 + i][k];
            float4 bv = *reinterpret_cast<const float4*>(&Ws[k][tx * 4]);
            float bb[4] = {bv.x, bv.y, bv.z, bv.w};
#pragma unroll
            for (int i = 0; i < 4; ++i)
#pragma unroll
                for (int j = 0; j < 4; ++j) acc[i][j] += av[i] * bb[j];
        }
        __syncthreads();
    }
    for (int i = 0; i < 4; ++i) {
        int m = m0 + ty * 4 + i;
        int n = n0 + tx * 4;
        float* Cp = C + (size_t)m * ldc + n;
        if (n + 3 < CD) {
            float4 v = {acc[i][0], acc[i][1], acc[i][2], acc[i][3]};
            *reinterpret_cast<float4*>(Cp) = v;
        } else {
            for (int j = 0; j < 4; ++j) if (n + j < CD) Cp[j] = acc[i][j];
        }
    }
}

// ---------- s1[r] = leaky(wc·a_top + X[r,:]·av), p[r] = X[r,:]·pv ----------
__global__ void k_score(const float* __restrict__ X, const float* __restrict__ av,
                        const float* __restrict__ pv, const float* __restrict__ wc,
                        const float* __restrict__ a_orig,
                        float alpha, float* __restrict__ s1, float* __restrict__ p, int M) {
    int gw = (blockIdx.x * blockDim.x + threadIdx.x) >> 6;
    int lane = threadIdx.x & 63;
    if (gw >= M) return;
    const float* row = X + (size_t)gw * CD;
    float d1 = 0.f, d2 = 0.f, dc = 0.f;
    for (int d = lane; d < CD; d += 64) {
        float x = row[d];
        d1 += x * av[d];
        d2 += x * pv[d];
        dc += wc[d] * a_orig[d];
    }
    for (int o = 32; o; o >>= 1) {
        d1 += __shfl_down(d1, o);
        d2 += __shfl_down(d2, o);
        dc += __shfl_down(dc, o);
    }
    if (lane == 0) {
        float v = dc + d1;
        s1[gw] = v > 0.f ? v : alpha * v;
        p[gw] = d2;
    }
}

// ---------- per-batch max over s1, e1 = exp(s1 - max) ----------
__global__ __launch_bounds__(1024) void k_bmax(const float* __restrict__ s1,
                                               float* __restrict__ e1) {
    __shared__ float red[16];
    int b = blockIdx.x, t = threadIdx.x;
    float v = s1[b * CN + t];
    float m = v;
    for (int o = 32; o; o >>= 1) m = fmaxf(m, __shfl_xor(m, o));
    if ((t & 63) == 0) red[t >> 6] = m;
    __syncthreads();
    if (t == 0) {
        float mm = red[0];
        for (int i = 1; i < 16; ++i) mm = fmaxf(mm, red[i]);
        red[0] = mm;
    }
    __syncthreads();
    e1[b * CN + t] = __expf(v - red[0]);
}

// ---------- sparse edge aggregation + fused q (CSR, unroll-8, XCD-pinned batches) ----------
// Block i -> batch b with b%8 == i%8 (bijective, 4096%8==0): each XCD's L2 keeps
// its 4 batches' X rows (~4.8 MB) resident across the ~51x per-row reuse.
__global__ __launch_bounds__(256) void k_edge_agg(const unsigned short* __restrict__ mem,
        const int* __restrict__ degs, const unsigned long long* __restrict__ ebits,
        const float* __restrict__ e1, const float* __restrict__ Xs,
        const float* __restrict__ qvec, float* __restrict__ edge, float* __restrict__ q) {
    int i0 = blockIdx.x;
    int r = i0 & 7, t = i0 >> 3;        // t in 0..511
    int b = (t >> 7) * 8 + r;           // 4 batches per XCD slot
    int j = t & 127;                    // edge-quad within batch
    int gw = b * CE + (j << 2) + (threadIdx.x >> 6);
    int lane = threadIdx.x & 63;
    const float* e1b = e1 + b * CN;
    const float* Xb = Xs + (size_t)b * CN * CD;
    int deg = degs[gw];
    float a0 = 0.f, a1 = 0.f, a2 = 0.f, a3 = 0.f, a4 = 0.f;
    float den = 0.f;
    bool tail = lane < (CD - 256);
    if (deg <= MCAP) {
        const unsigned short* lst = mem + (size_t)gw * MCAP;
        int i = 0;
        for (; i + 8 <= deg; i += 8) {
            ushort4 na = *reinterpret_cast<const ushort4*>(lst + i);
            ushort4 nb = *reinterpret_cast<const ushort4*>(lst + i + 4);
            float w0 = e1b[na.x], w1 = e1b[na.y], w2 = e1b[na.z], w3 = e1b[na.w];
            float w4 = e1b[nb.x], w5 = e1b[nb.y], w6 = e1b[nb.z], w7 = e1b[nb.w];
            const float* r0 = Xb + (size_t)na.x * CD;
            const float* r1 = Xb + (size_t)na.y * CD;
            const float* r2 = Xb + (size_t)na.z * CD;
            const float* r3 = Xb + (size_t)na.w * CD;
            const float* r4 = Xb + (size_t)nb.x * CD;
            const float* r5 = Xb + (size_t)nb.y * CD;
            const float* r6 = Xb + (size_t)nb.z * CD;
            const float* r7 = Xb + (size_t)nb.w * CD;
            float v00 = r0[lane], v01 = r0[lane + 64], v02 = r0[lane + 128], v03 = r0[lane + 192];
            float v10 = r1[lane], v11 = r1[lane + 64], v12 = r1[lane + 128], v13 = r1[lane + 192];
            float v20 = r2[lane], v21 = r2[lane + 64], v22 = r2[lane + 128], v23 = r2[lane + 192];
            float v30 = r3[lane], v31 = r3[lane + 64], v32 = r3[lane + 128], v33 = r3[lane + 192];
            float v40 = r4[lane], v41 = r4[lane + 64], v42 = r4[lane + 128], v43 = r4[lane + 192];
            float v50 = r5[lane], v51 = r5[lane + 64], v52 = r5[lane + 128], v53 = r5[lane + 192];
            float v60 = r6[lane], v61 = r6[lane + 64], v62 = r6[lane + 128], v63 = r6[lane + 192];
            float v70 = r7[lane], v71 = r7[lane + 64], v72 = r7[lane + 128], v73 = r7[lane + 192];
            float v04 = 0.f, v14 = 0.f, v24 = 0.f, v34 = 0.f;
            float v44 = 0.f, v54 = 0.f, v64 = 0.f, v74 = 0.f;
            if (tail) {
                v04 = r0[lane + 256]; v14 = r1[lane + 256]; v24 = r2[lane + 256]; v34 = r3[lane + 256];
                v44 = r4[lane + 256]; v54 = r5[lane + 256]; v64 = r6[lane + 256]; v74 = r7[lane + 256];
            }
            den += w0; den += w1; den += w2; den += w3;
            den += w4; den += w5; den += w6; den += w7;
            a0 += w0 * v00; a0 += w1 * v10; a0 += w2 * v20; a0 += w3 * v30;
            a0 += w4 * v40; a0 += w5 * v50; a0 += w6 * v60; a0 += w7 * v70;
            a1 += w0 * v01; a1 += w1 * v11; a1 += w2 * v21; a1 += w3 * v31;
            a1 += w4 * v41; a1 += w5 * v51; a1 += w6 * v61; a1 += w7 * v71;
            a2 += w0 * v02; a2 += w1 * v12; a2 += w2 * v22; a2 += w3 * v32;
            a2 += w4 * v42; a2 += w5 * v52; a2 += w6 * v62; a2 += w7 * v72;
            a3 += w0 * v03; a3 += w1 * v13; a3 += w2 * v23; a3 += w3 * v33;
            a3 += w4 * v43; a3 += w5 * v53; a3 += w6 * v63; a3 += w7 * v73;
            a4 += w0 * v04; a4 += w1 * v14; a4 += w2 * v24; a4 += w3 * v34;
            a4 += w4 * v44; a4 += w5 * v54; a4 += w6 * v64; a4 += w7 * v74;
        }
        for (; i + 4 <= deg; i += 4) {
            ushort4 nn = *reinterpret_cast<const ushort4*>(lst + i);
            float w0 = e1b[nn.x], w1 = e1b[nn.y], w2 = e1b[nn.z], w3 = e1b[nn.w];
            const float* r0 = Xb + (size_t)nn.x * CD;
            const float* r1 = Xb + (size_t)nn.y * CD;
            const float* r2 = Xb + (size_t)nn.z * CD;
            const float* r3 = Xb + (size_t)nn.w * CD;
            float v00 = r0[lane], v01 = r0[lane + 64], v02 = r0[lane + 128], v03 = r0[lane + 192];
            float v10 = r1[lane], v11 = r1[lane + 64], v12 = r1[lane + 128], v13 = r1[lane + 192];
            float v20 = r2[lane], v21 = r2[lane + 64], v22 = r2[lane + 128], v23 = r2[lane + 192];
            float v30 = r3[lane], v31 = r3[lane + 64], v32 = r3[lane + 128], v33 = r3[lane + 192];
            float v04 = 0.f, v14 = 0.f, v24 = 0.f, v34 = 0.f;
            if (tail) { v04 = r0[lane + 256]; v14 = r1[lane + 256]; v24 = r2[lane + 256]; v34 = r3[lane + 256]; }
            den += w0; den += w1; den += w2; den += w3;
            a0 += w0 * v00; a0 += w1 * v10; a0 += w2 * v20; a0 += w3 * v30;
            a1 += w0 * v01; a1 += w1 * v11; a1 += w2 * v21; a1 += w3 * v31;
            a2 += w0 * v02; a2 += w1 * v12; a2 += w2 * v22; a2 += w3 * v32;
            a3 += w0 * v03; a3 += w1 * v13; a3 += w2 * v23; a3 += w3 * v33;
            a4 += w0 * v04; a4 += w1 * v14; a4 += w2 * v24; a4 += w3 * v34;
        }
        for (; i < deg; ++i) {
            int n = lst[i];
            float w = e1b[n];
            const float* r = Xb + (size_t)n * CD;
            den += w;
            a0 += w * r[lane];
            a1 += w * r[lane + 64];
            a2 += w * r[lane + 128];
            a3 += w * r[lane + 192];
            if (tail) a4 += w * r[lane + 256];
        }
    } else {   // overflow fallback (P~1e-20): ebits/ballot path
        const unsigned long long* eb = ebits + (size_t)gw * 16;
#pragma unroll
        for (int c = 0; c < 16; ++c) {
            int n0 = c << 6;
            float wv = e1b[n0 + lane];
            unsigned long long bal = eb[c];
            while (bal) {
                int jj = (int)__ffsll(bal) - 1;
                bal &= bal - 1ull;
                float w = __shfl(wv, jj);
                const float* row = Xb + (size_t)(n0 + jj) * CD;
                den += w;
                a0 += w * row[lane];
                a1 += w * row[lane + 64];
                a2 += w * row[lane + 128];
                a3 += w * row[lane + 192];
                if (tail) a4 += w * row[lane + 256];
            }
        }
    }
    float inv = deg > 0 ? 1.f / den : 0.f;
    float o0 = a0 * inv, o1 = a1 * inv, o2 = a2 * inv, o3 = a3 * inv;
    float o4 = tail ? a4 * inv : 0.f;
    float* erow = edge + (size_t)gw * EP;
    erow[lane]       = o0;
    erow[lane + 64]  = o1;
    erow[lane + 128] = o2;
    erow[lane + 192] = o3;
    erow[lane + 256] = o4;   // lanes 44..63 zero floats 300..319
    float d2 = o0 * qvec[lane];
    d2 += o1 * qvec[lane + 64];
    d2 += o2 * qvec[lane + 128];
    d2 += o3 * qvec[lane + 192];
    if (tail) d2 += o4 * qvec[lane + 256];
    for (int o = 32; o; o >>= 1) d2 += __shfl_down(d2, o);
    if (lane == 0) q[gw] = d2;
}

// ---------- fused node attention (R8-proven): nbits masks + compacted weights ----------
#define ACC16(vv, ww) do { \
    acc[0][0] += (ww).x * (vv).x; acc[0][1] += (ww).x * (vv).y; \
    acc[0][2] += (ww).x * (vv).z; acc[0][3] += (ww).x * (vv).w; \
    acc[1][0] += (ww).y * (vv).x; acc[1][1] += (ww).y * (vv).y; \
    acc[1][2] += (ww).y * (vv).z; acc[1][3] += (ww).y * (vv).w; \
    acc[2][0] += (ww).z * (vv).x; acc[2][1] += (ww).z * (vv).y; \
    acc[2][2] += (ww).z * (vv).z; acc[2][3] += (ww).z * (vv).w; \
    acc[3][0] += (ww).w * (vv).x; acc[3][1] += (ww).w * (vv).y; \
    acc[3][2] += (ww).w * (vv).z; acc[3][3] += (ww).w * (vv).w; \
} while (0)

__global__ __launch_bounds__(320) void k_node_attn(const unsigned long long* __restrict__ nbits,
        const float* __restrict__ p, const float* __restrict__ q,
        const float* __restrict__ edge, float alpha, int do_elu, float* __restrict__ out) {
    __shared__ float4 wsc[4][UCAP];
    __shared__ __align__(8) unsigned short ul[4][UCAP];
    __shared__ int ucnt_s[4], flag_s[4];
    __shared__ float gpn[16], gmx[16], gsc[16];
    __shared__ int gct[16];
    int blk = blockIdx.x;
    int b = blk >> 6, n0 = (blk & 63) << 4;
    int tid = threadIdx.x, wv = tid >> 6, lane = tid & 63;
    const float* qb = q + b * CE;

    if (wv < 4) {
        float pn[4]; const unsigned long long* nb[4];
#pragma unroll
        for (int k = 0; k < 4; ++k) {
            int n = n0 + 4 * wv + k;
            pn[k] = p[b * CN + n];
            nb[k] = nbits + ((size_t)b * CN + n) * 8;
        }
        float sc[4][8];
        int cnt[4] = {0, 0, 0, 0};
        float mx[4] = {-3.4e38f, -3.4e38f, -3.4e38f, -3.4e38f};
        int ubits = 0;
#pragma unroll
        for (int j = 0; j < 8; ++j) {
            int e = lane + (j << 6);
            float qe = qb[e];
            int many = 0;
#pragma unroll
            for (int k = 0; k < 4; ++k) {
                int m = (int)((nb[k][j] >> lane) & 1ull);
                float v = pn[k] + qe;
                v = v > 0.f ? v : alpha * v;
                v = m ? v : -3.0e38f;
                cnt[k] += m; many |= m;
                mx[k] = fmaxf(mx[k], v);
                sc[k][j] = v;
            }
            ubits |= (many ? 1 : 0) << j;
        }
#pragma unroll
        for (int k = 0; k < 4; ++k) {
            for (int o = 32; o; o >>= 1) {
                mx[k] = fmaxf(mx[k], __shfl_xor(mx[k], o));
                cnt[k] += __shfl_xor(cnt[k], o);
            }
        }
        float scale[4];
#pragma unroll
        for (int k = 0; k < 4; ++k) {
            float s = 0.f;
#pragma unroll
            for (int j = 0; j < 8; ++j) { float w8 = __expf(sc[k][j] - mx[k]); sc[k][j] = w8; s += w8; }
            for (int o = 32; o; o >>= 1) s += __shfl_xor(s, o);
            scale[k] = cnt[k] > 0 ? 1.f / s : 1.f;
        }
        int base = 0;
        unsigned long long lmask = (1ull << lane) - 1ull;
#pragma unroll
        for (int j = 0; j < 8; ++j) {
            unsigned long long bal = __ballot((ubits >> j) & 1);
            if ((ubits >> j) & 1) {
                int off = base + (int)__popcll(bal & lmask);
                if (off < UCAP) {
                    ul[wv][off] = (unsigned short)(lane + (j << 6));
                    wsc[wv][off] = make_float4(sc[0][j] * scale[0], sc[1][j] * scale[1],
                                               sc[2][j] * scale[2], sc[3][j] * scale[3]);
                }
            }
            base += (int)__popcll(bal);
        }
        if (lane == 0) {
            ucnt_s[wv] = base < UCAP ? base : UCAP;
            flag_s[wv] = (cnt[0] == 0) | (cnt[1] == 0) | (cnt[2] == 0) | (cnt[3] == 0) |
                         (base > UCAP);
            gpn[wv*4+0]=pn[0]; gmx[wv*4+0]=mx[0]; gsc[wv*4+0]=scale[0]; gct[wv*4+0]=cnt[0];
            gpn[wv*4+1]=pn[1]; gmx[wv*4+1]=mx[1]; gsc[wv*4+1]=scale[1]; gct[wv*4+1]=cnt[1];
            gpn[wv*4+2]=pn[2]; gmx[wv*4+2]=mx[2]; gsc[wv*4+2]=scale[2]; gct[wv*4+2]=cnt[2];
            gpn[wv*4+3]=pn[3]; gmx[wv*4+3]=mx[3]; gsc[wv*4+3]=scale[3]; gct[wv*4+3]=cnt[3];
        }
    }
    __syncthreads();

    int grp = tid / 80;
    int j4 = tid - grp * 80;
    const float4* eb4 = reinterpret_cast<const float4*>(edge + (size_t)b * CE * EP) + j4;
    int cnt = ucnt_s[grp], bad = flag_s[grp];
    float acc[4][4] = {};
    if (!bad) {
        int i = 0;
        for (; i + 8 <= cnt; i += 8) {
            ushort4 ua = *reinterpret_cast<const ushort4*>(&ul[grp][i]);
            ushort4 ub = *reinterpret_cast<const ushort4*>(&ul[grp][i + 4]);
            float4 v0 = eb4[(size_t)ua.x * 80], v1 = eb4[(size_t)ua.y * 80];
            float4 v2 = eb4[(size_t)ua.z * 80], v3 = eb4[(size_t)ua.w * 80];
            float4 v4 = eb4[(size_t)ub.x * 80], v5 = eb4[(size_t)ub.y * 80];
            float4 v6 = eb4[(size_t)ub.z * 80], v7 = eb4[(size_t)ub.w * 80];
            { float4 w = wsc[grp][i];     ACC16(v0, w); }
            { float4 w = wsc[grp][i + 1]; ACC16(v1, w); }
            { float4 w = wsc[grp][i + 2]; ACC16(v2, w); }
            { float4 w = wsc[grp][i + 3]; ACC16(v3, w); }
            { float4 w = wsc[grp][i + 4]; ACC16(v4, w); }
            { float4 w = wsc[grp][i + 5]; ACC16(v5, w); }
            { float4 w = wsc[grp][i + 6]; ACC16(v6, w); }
            { float4 w = wsc[grp][i + 7]; ACC16(v7, w); }
        }
        for (; i < cnt; ++i) {
            int e = ul[grp][i];
            float4 v = eb4[(size_t)e * 80];
            float4 w = wsc[grp][i];
            ACC16(v, w);
        }
    } else {
        float pnk[4], mxk[4], sck[4]; int ctk[4];
        const unsigned long long* nbr[4];
#pragma unroll
        for (int k = 0; k < 4; ++k) {
            pnk[k] = gpn[grp*4+k]; mxk[k] = gmx[grp*4+k]; sck[k] = gsc[grp*4+k]; ctk[k] = gct[grp*4+k];
            nbr[k] = nbits + ((size_t)b * CN + n0 + grp * 4 + k) * 8;
        }
        for (int e = 0; e < CE; ++e) {
            float4 v = eb4[(size_t)e * 80];
            float qe = qb[e];
#pragma unroll
            for (int k = 0; k < 4; ++k) {
                int m = (int)((nbr[k][e >> 6] >> (e & 63)) & 1ull);
                float vv = pnk[k] + qe; vv = vv > 0.f ? vv : alpha * vv;
                float w = ctk[k] == 0 ? (1.f / CE) : (m ? __expf(vv - mxk[k]) * sck[k] : 0.f);
                acc[k][0] += w * v.x; acc[k][1] += w * v.y; acc[k][2] += w * v.z; acc[k][3] += w * v.w;
            }
        }
    }
    if (j4 < 75) {
#pragma unroll
        for (int ni = 0; ni < 4; ++ni) {
            float4 o = {acc[ni][0], acc[ni][1], acc[ni][2], acc[ni][3]};
            if (do_elu) {
                o.x = o.x > 0.f ? o.x : expm1f(o.x);
                o.y = o.y > 0.f ? o.y : expm1f(o.y);
                o.z = o.z > 0.f ? o.z : expm1f(o.z);
                o.w = o.w > 0.f ? o.w : expm1f(o.w);
            }
            *reinterpret_cast<float4*>(out + ((size_t)b * CN + n0 + grp * 4 + ni) * CD + j4 * 4) = o;
        }
    }
}

extern "C" void kernel_launch(void* const* d_in, const int* in_sizes, int n_in,
                              void* d_out, int out_size, void* d_ws, size_t ws_size,
                              hipStream_t stream) {
    const int*   inputs = (const int*)d_in[0];
    const int*   HT     = (const int*)d_in[1];
    const float* emb    = (const float*)d_in[2];
    const float* w2_1   = (const float*)d_in[3];
    const float* w3_1   = (const float*)d_in[4];
    const float* a_1    = (const float*)d_in[5];
    const float* a2_1   = (const float*)d_in[6];
    const float* wc_1   = (const float*)d_in[7];
    const float* w_2    = (const float*)d_in[8];
    const float* w2_2   = (const float*)d_in[9];
    const float* w3_2   = (const float*)d_in[10];
    const float* a_2    = (const float*)d_in[11];
    const float* a2_2   = (const float*)d_in[12];
    const float* wc_2   = (const float*)d_in[13];

    char* ws = (char*)d_ws;
    float* big0               = (float*)(ws);                          // 39,321,600 B: X0 -> X1
    float* big1               = (float*)(ws + 39321600);               // 39,321,600 B: XW
    float* edge               = (float*)(ws + 78643200);               // 20,971,520 B (EP=320)
    unsigned long long* ebits = (unsigned long long*)(ws + 99614720);  //  2,097,152 B
    unsigned long long* nbits = (unsigned long long*)(ws + 101711872); //  2,097,152 B
    unsigned short* mem       = (unsigned short*)(ws + 103809024);     //  6,291,456 B
    int* degs                 = (int*)(ws + 110100480);                //     65,536 B
    float* s1                 = (float*)(ws + 110166016);              //    131,072 B
    float* p                  = (float*)(ws + 110297088);              //    131,072 B
    float* e1                 = (float*)(ws + 110428160);              //    131,072 B
    float* qv                 = (float*)(ws + 110559232);              //     65,536 B
    float* vecs               = (float*)(ws + 110624768);              //      7,200 B
    // total: 110,631,968 B

    k_embed<<<9600, 256, 0, stream>>>(inputs, emb, big0);
    k_ebits_mem<<<4096, 256, 0, stream>>>(HT, ebits, mem, degs);
    k_bitT<<<512, 512, 0, stream>>>(ebits, nbits);
    k_prep<<<6, 320, 0, stream>>>(w2_1, w3_1, a_1, a2_1, w2_2, w3_2, a_2, a2_2, vecs);

    // ---- layer 1: transfer=False, concat=True (ELU), alpha=0.1 ----
    k_score<<<CB * CN / 4, 256, 0, stream>>>(big0, vecs, vecs + CD, wc_1, a_1, 0.1f, s1, p, CB * CN);
    k_bmax<<<CB, 1024, 0, stream>>>(s1, e1);
    k_edge_agg<<<4096, 256, 0, stream>>>(mem, degs, ebits, e1, big0, vecs + 2 * CD, edge, qv);
    k_node_attn<<<2048, 320, 0, stream>>>(nbits, p, qv, edge, 0.1f, 1, big0);   // X1 -> big0

    // ---- layer 2: transfer=True, concat=False, alpha=0.2 ----
    k_score<<<CB * CN / 4, 256, 0, stream>>>(big0, vecs + 3 * CD, vecs + 4 * CD, wc_2, a_2, 0.2f, s1, p, CB * CN);
    k_gemm300<<<dim3(5, 512), 256, 0, stream>>>(big0, w_2, big1, CB * CN, CD, CD);   // XW = X1 @ w_2
    k_bmax<<<CB, 1024, 0, stream>>>(s1, e1);
    k_edge_agg<<<4096, 256, 0, stream>>>(mem, degs, ebits, e1, big1, vecs + 5 * CD, edge, qv);
    k_node_attn<<<2048, 320, 0, stream>>>(nbits, p, qv, edge, 0.2f, 0, (float*)d_out);
}